// Round 22
// baseline (287.040 us; speedup 1.0000x reference)
//
#include <hip/hip_runtime.h>

// Problem constants (B,N,M,D) = (16,1024,4096,256), all fp32.
// Strategy: cross-GEMM on matrix cores via exact 2-term fp16 split
// (e = ae+be, t*2^17 = at+bt), 3 MFMA products ae*at + ae*bt + be*at,
// splits precomputed. Round 22: r21's static-addressed dbuf+DMA+1-barrier
// pipeline with the VGPR diet (r21: VALU 53.6->14.5% proven, but VGPR
// 124->148 crossed the 128 cliff, occ 20->11%):
//  (1) best/bidx[16] (32 VGPR) -> owner-exclusive 2KB LDS table, per-ct
//      epilogue reduce+merge (r12's mechanism, passed absmax=0; cross-ct
//      tie->stored keeps min index since ct ascends).
//  (2) 64-bit per-lane pointers -> 32-bit offsets + SGPR bases (saddr
//      form; kc offsets <=448B fold into the 13-bit imm).
// Numerics FROZEN (absmax=0 rounds 6-21): DMA staging is a bitwise copy,
// identical MFMA product/k order (p1=hi*hi, p2=hi*Tlo, p3=Elo*hi),
// identical epilogue d2 = fl(fl(esq-2*cross)+tsq), ascending-column
// candidate order, strict '<' + min-index ties, np-pairwise esq/tsq.

typedef _Float16 half8 __attribute__((ext_vector_type(8)));
typedef float f32x4 __attribute__((ext_vector_type(4)));

constexpr int B_ = 16, N_ = 1024, M_ = 4096, D_ = 256;
constexpr int ROWS = B_ * N_;      // 16384 query rows
constexpr int BR = 128;            // rows per block
constexpr int BC = 128;            // cols per col-tile
constexpr int NCT = 4;             // col-tiles per block
constexpr int CS = 8;              // col splits (blockIdx.y)
constexpr int CPB = BC * NCT;      // 512 cols per block
constexpr int KC = 32;             // k per chunk = one 16x16x32 MFMA-K
constexpr int LDH = 32;            // LDS halfs/row: 64B rows
constexpr int NPART = CS * 2;      // 16 partials per row (2 col-half waves)
constexpr float TSCALE = 131072.0f;        // 2^17 (exact)
constexpr float INV2 = 1.52587890625e-05f; // 2^-16: acc*2^-16 == 2*cross, exact

// Direct global->LDS DMA, 16B per lane (dest = wave-uniform base + lane*16).
__device__ __forceinline__ void gload16(const _Float16* g, _Float16* l) {
    __builtin_amdgcn_global_load_lds(
        (const __attribute__((address_space(1))) void*)g,
        (__attribute__((address_space(3))) void*)l, 16, 0, 0);
}

// ---------------------------------------------------------------------------
// Kernel 0: one-time hi/lo fp16 split of E and T (T scaled by 2^17, exact).
// ---------------------------------------------------------------------------
__global__ void split_kernel(const float* __restrict__ E, const float* __restrict__ T,
                             _Float16* __restrict__ Ehi, _Float16* __restrict__ Elo,
                             _Float16* __restrict__ Thi, _Float16* __restrict__ Tlo) {
    int idx = blockIdx.x * blockDim.x + threadIdx.x;
    int row = idx >> 5;            // 32 threads per 256-elem row
    int c8 = (idx & 31) * 8;
    if (row >= ROWS + M_) return;
    const float* src;
    _Float16 *hi, *lo;
    size_t off;
    float scale;
    if (row < ROWS) {
        off = (size_t)row * D_ + c8;
        src = E + off; hi = Ehi; lo = Elo; scale = 1.0f;
    } else {
        off = (size_t)(row - ROWS) * D_ + c8;
        src = T + off; hi = Thi; lo = Tlo; scale = TSCALE;
    }
    float x[8];
    *reinterpret_cast<float4*>(&x[0]) = *reinterpret_cast<const float4*>(src);
    *reinterpret_cast<float4*>(&x[4]) = *reinterpret_cast<const float4*>(src + 4);
    half8 h, l;
    #pragma unroll
    for (int j = 0; j < 8; j++) {
        float xs = x[j] * scale;               // exact for T (pow2), 1.0 for E
        _Float16 hh = (_Float16)xs;            // RN
        h[j] = hh;
        l[j] = (_Float16)(xs - (float)hh);
    }
    *reinterpret_cast<half8*>(hi + off) = h;
    *reinterpret_cast<half8*>(lo + off) = l;
}

// ---------------------------------------------------------------------------
// Kernel 1 (FROZEN): row sum-of-squares, numpy pairwise bit-exact for n=256.
// ---------------------------------------------------------------------------
__global__ void rowsq_kernel(const float* __restrict__ E, const float* __restrict__ T,
                             float* __restrict__ esq, float* __restrict__ tsq) {
    int gt = blockIdx.x * blockDim.x + threadIdx.x;
    int row = gt >> 4;
    int l = gt & 15;
    if (row >= ROWS + M_) return;
    const float* src = (row < ROWS) ? (E + (size_t)row * D_)
                                    : (T + (size_t)(row - ROWS) * D_);
    const float* p = src + (l >> 3) * 128 + (l & 7);
    float r = __fmul_rn(p[0], p[0]);
    #pragma unroll
    for (int i = 1; i < 16; i++) {
        float x = p[8 * i];
        r = __fadd_rn(r, __fmul_rn(x, x));
    }
    float u = __fadd_rn(r, __shfl_xor(r, 1, 64));
    float v = __fadd_rn(u, __shfl_xor(u, 2, 64));
    float w = __fadd_rn(v, __shfl_xor(v, 4, 64));
    float s = __fadd_rn(w, __shfl_xor(w, 8, 64));
    if (l == 0) {
        if (row < ROWS) esq[row] = s;
        else            tsq[row - ROWS] = s;
    }
}

// ---------------------------------------------------------------------------
// Kernel 2: MFMA fused GEMM + argmin of d2 = fl(fl(esq - 2*cross) + tsq).
// 256 threads = 4 waves (2x2 of 64x64); wave = 4x4 frags of 16x16x32_f16.
// Double-buffered LDS, global_load_lds DMA, ONE barrier per chunk,
// ct-outer / k-unrolled, 32-bit offsets, per-ct LDS best-table epilogue.
// ---------------------------------------------------------------------------
__global__ __launch_bounds__(256) void score_kernel(
    const _Float16* __restrict__ Ehi_g, const _Float16* __restrict__ Elo_g,
    const _Float16* __restrict__ Thi_g, const _Float16* __restrict__ Tlo_g,
    const float* __restrict__ esq, const float* __restrict__ tsq,
    float2* __restrict__ part) {
    __shared__ _Float16 Eh[2][BR][LDH];
    __shared__ _Float16 El[2][BR][LDH];
    __shared__ _Float16 Th[2][BC][LDH];
    __shared__ _Float16 Tl[2][BC][LDH];
    __shared__ float2 bestLds[BR][2];   // (local row, wc) -> running (v, idx)

    const int tid = threadIdx.x;
    const int w  = tid >> 6;       // wave 0..3
    const int l  = tid & 63;
    const int wr = w >> 1;         // row half (0/1)
    const int wc = w & 1;          // col half (0/1)
    const int q  = l >> 4;         // lane quarter
    const int cl = l & 15;         // col-in-frag
    const int row0 = blockIdx.x * BR;
    const int cs = blockIdx.y;
    const int colB = cs * CPB;

    const int lrow = l >> 2;           // 0..15
    const int lk   = (l & 3) * 8;      // 0,8,16,24 (halfs)

    // 32-bit per-lane source offsets (halfs); bases stay in SGPRs.
    const int offE  = (row0 + 32 * w + lrow) * D_ + lk;
    const int offE2 = offE + 16 * D_;
    int offT  = (colB + 32 * w + lrow) * D_ + lk;
    int offT2 = offT + 16 * D_;
    constexpr int TSTEP = BC * D_;     // next ct (halfs)

    // Wave-uniform LDS staging dest bases.
    _Float16* dEh0 = &Eh[0][32 * w][0];      _Float16* dEh1 = &Eh[0][32 * w + 16][0];
    _Float16* dEl0 = &El[0][32 * w][0];      _Float16* dEl1 = &El[0][32 * w + 16][0];
    _Float16* dTh0 = &Th[0][32 * w][0];      _Float16* dTh1 = &Th[0][32 * w + 16][0];
    _Float16* dTl0 = &Tl[0][32 * w][0];      _Float16* dTl1 = &Tl[0][32 * w + 16][0];
    constexpr int BUFO = BR * LDH;           // halfs between buf 0 and buf 1

    // Init owner-exclusive best slots (cl==0 lanes own slot [lr][wc]).
    if (cl == 0) {
        #pragma unroll
        for (int fr = 0; fr < 4; fr++)
            #pragma unroll
            for (int rg = 0; rg < 4; rg++)
                bestLds[wr * 64 + fr * 16 + q * 4 + rg][wc] =
                    make_float2(3.4e38f, __int_as_float(0));
    }

    f32x4 acc[4][4];

    // Prologue: stage chunk 0 (ct=0, kc=0) into buf 0.
    gload16(Ehi_g + offE, dEh0); gload16(Ehi_g + offE2, dEh1);
    gload16(Elo_g + offE, dEl0); gload16(Elo_g + offE2, dEl1);
    gload16(Thi_g + offT, dTh0); gload16(Thi_g + offT2, dTh1);
    gload16(Tlo_g + offT, dTl0); gload16(Tlo_g + offT2, dTl1);
    __syncthreads();

    for (int ct = 0; ct < NCT; ct++) {
        #pragma unroll
        for (int i = 0; i < 4; i++)
            #pragma unroll
            for (int j = 0; j < 4; j++)
                acc[i][j] = (f32x4){0.f, 0.f, 0.f, 0.f};

        #pragma unroll
        for (int k = 0; k < 8; k++) {
            const int b = k & 1;           // compile-time per body
            const int dst = (b ^ 1) * BUFO;

            // --- STAGE next chunk into the other buffer ---
            if (k < 7) {
                const int nkc = (k + 1) * KC;   // 32..224 halfs (imm-foldable)
                gload16(Ehi_g + offE + nkc, dEh0 + dst); gload16(Ehi_g + offE2 + nkc, dEh1 + dst);
                gload16(Elo_g + offE + nkc, dEl0 + dst); gload16(Elo_g + offE2 + nkc, dEl1 + dst);
                gload16(Thi_g + offT + nkc, dTh0 + dst); gload16(Thi_g + offT2 + nkc, dTh1 + dst);
                gload16(Tlo_g + offT + nkc, dTl0 + dst); gload16(Tlo_g + offT2 + nkc, dTl1 + dst);
            } else if (ct < NCT - 1) {
                gload16(Ehi_g + offE, dEh0 + dst); gload16(Ehi_g + offE2, dEh1 + dst);
                gload16(Elo_g + offE, dEl0 + dst); gload16(Elo_g + offE2, dEl1 + dst);
                gload16(Thi_g + offT + TSTEP, dTh0 + dst); gload16(Thi_g + offT2 + TSTEP, dTh1 + dst);
                gload16(Tlo_g + offT + TSTEP, dTl0 + dst); gload16(Tlo_g + offT2 + TSTEP, dTl1 + dst);
            }

            // --- compute from buf b; MFMA order FROZEN: hi*hi, hi*Tlo, Elo*hi ---
            half8 ah[4], bh[4], tmp[4];
            #pragma unroll
            for (int f = 0; f < 4; f++)
                ah[f] = *reinterpret_cast<const half8*>(&Eh[b][wr * 64 + f * 16 + cl][q * 8]);
            #pragma unroll
            for (int f = 0; f < 4; f++)
                bh[f] = *reinterpret_cast<const half8*>(&Th[b][wc * 64 + f * 16 + cl][q * 8]);
            #pragma unroll
            for (int i = 0; i < 4; i++)
                #pragma unroll
                for (int j = 0; j < 4; j++)
                    acc[i][j] = __builtin_amdgcn_mfma_f32_16x16x32_f16(ah[i], bh[j], acc[i][j], 0, 0, 0);
            #pragma unroll
            for (int f = 0; f < 4; f++)
                tmp[f] = *reinterpret_cast<const half8*>(&Tl[b][wc * 64 + f * 16 + cl][q * 8]);
            #pragma unroll
            for (int i = 0; i < 4; i++)
                #pragma unroll
                for (int j = 0; j < 4; j++)
                    acc[i][j] = __builtin_amdgcn_mfma_f32_16x16x32_f16(ah[i], tmp[j], acc[i][j], 0, 0, 0);
            #pragma unroll
            for (int i = 0; i < 4; i++) {
                half8 t = *reinterpret_cast<const half8*>(&El[b][wr * 64 + i * 16 + cl][q * 8]);
                #pragma unroll
                for (int j = 0; j < 4; j++)
                    acc[i][j] = __builtin_amdgcn_mfma_f32_16x16x32_f16(t, bh[j], acc[i][j], 0, 0, 0);
            }

            // --- per-ct epilogue (k==7): reduce each slot, merge into LDS ---
            // Within-thread cols ascend over fc; strict '<' keeps min index;
            // cross-ct merge tie->stored keeps the earlier (smaller) index.
            if (k == 7) {
                const int col0 = colB + ct * BC;
                float tc4[4];
                #pragma unroll
                for (int fc = 0; fc < 4; fc++)
                    tc4[fc] = tsq[col0 + wc * 64 + fc * 16 + cl];
                #pragma unroll
                for (int fr = 0; fr < 4; fr++)
                    #pragma unroll
                    for (int rg = 0; rg < 4; rg++) {
                        const float er = esq[row0 + wr * 64 + fr * 16 + q * 4 + rg];
                        float v = 3.4e38f; int bi = 0;
                        #pragma unroll
                        for (int fc = 0; fc < 4; fc++) {
                            const float c2 = acc[fr][fc][rg] * INV2;  // exact
                            const float d1 = __fsub_rn(er, c2);
                            const float d2 = __fadd_rn(d1, tc4[fc]);
                            if (d2 < v) { v = d2; bi = col0 + wc * 64 + fc * 16 + cl; }
                        }
                        #pragma unroll
                        for (int off = 1; off < 16; off <<= 1) {
                            float ov = __shfl_xor(v, off, 64);
                            int   oi = __shfl_xor(bi, off, 64);
                            if (ov < v || (ov == v && oi < bi)) { v = ov; bi = oi; }
                        }
                        if (cl == 0) {
                            const int lr = wr * 64 + fr * 16 + q * 4 + rg;
                            float2 cur = bestLds[lr][wc];
                            int ci = __float_as_int(cur.y);
                            if (v < cur.x || (v == cur.x && bi < ci))
                                bestLds[lr][wc] = make_float2(v, __int_as_float(bi));
                        }
                    }
            }

            __syncthreads();   // drains vmcnt: next buf filled, buf b reusable
        }
        offT  += TSTEP;
        offT2 += TSTEP;
    }

    // Final: owners write their merged partials.
    if (cl == 0) {
        #pragma unroll
        for (int fr = 0; fr < 4; fr++)
            #pragma unroll
            for (int rg = 0; rg < 4; rg++) {
                const int lr = wr * 64 + fr * 16 + q * 4 + rg;
                part[(size_t)(row0 + lr) * NPART + cs * 2 + wc] = bestLds[lr][wc];
            }
    }
}

// ---------------------------------------------------------------------------
// Kernel 3: reduce NPART partials per row (min value, min index on ties),
// gather quant = templat[idx] (bitwise copy), write zidx as float.
// ---------------------------------------------------------------------------
__global__ void gather_kernel(const float* __restrict__ T, const float2* __restrict__ part,
                              float* __restrict__ quant, float* __restrict__ zout) {
    int gt = blockIdx.x * blockDim.x + threadIdx.x;
    int w = gt >> 6, lane = gt & 63;
    if (w >= ROWS) return;
    float2 p = part[(size_t)w * NPART];
    float v = p.x; int idx = __float_as_int(p.y);
    #pragma unroll
    for (int c = 1; c < NPART; c++) {
        float2 q = part[(size_t)w * NPART + c];
        int qi = __float_as_int(q.y);
        if (q.x < v || (q.x == v && qi < idx)) { v = q.x; idx = qi; }
    }
    float4 t = *reinterpret_cast<const float4*>(T + (size_t)idx * D_ + lane * 4);
    *reinterpret_cast<float4*>(quant + (size_t)w * D_ + lane * 4) = t;
    if (lane == 0) zout[w] = (float)idx;
}

// ---------------------------------------------------------------------------
extern "C" void kernel_launch(void* const* d_in, const int* in_sizes, int n_in,
                              void* d_out, int out_size, void* d_ws, size_t ws_size,
                              hipStream_t stream) {
    const float* E = (const float*)d_in[0];   // encode  (B,N,D)
    const float* T = (const float*)d_in[1];   // templat (M,D)
    float* quant = (float*)d_out;                        // (B,N,D) fp32
    float* zout  = quant + (size_t)ROWS * D_;            // (B,N) idx as fp32

    // ws layout: esq[ROWS], tsq[M], part[ROWS*NPART], fp16 Ehi/Elo/Thi/Tlo.
    float* esq   = (float*)d_ws;
    float* tsq   = esq + ROWS;
    float2* part = (float2*)(tsq + M_);
    _Float16* Ehi = (_Float16*)(part + (size_t)ROWS * NPART);
    _Float16* Elo = Ehi + (size_t)ROWS * D_;
    _Float16* Thi = Elo + (size_t)ROWS * D_;
    _Float16* Tlo = Thi + (size_t)M_ * D_;

    hipLaunchKernelGGL(split_kernel, dim3((ROWS + M_) * 32 / 256), dim3(256), 0, stream,
                       E, T, Ehi, Elo, Thi, Tlo);
    hipLaunchKernelGGL(rowsq_kernel, dim3((ROWS + M_) * 16 / 256), dim3(256), 0, stream, E, T, esq, tsq);
    hipLaunchKernelGGL(score_kernel, dim3(ROWS / BR, CS), dim3(256), 0, stream,
                       Ehi, Elo, Thi, Tlo, esq, tsq, part);
    hipLaunchKernelGGL(gather_kernel, dim3(ROWS * 64 / 256), dim3(256), 0, stream, T, part, quant, zout);
}

// Round 23
// 152.773 us; speedup vs baseline: 1.8789x; 1.8789x over previous
//
#include <hip/hip_runtime.h>

// Problem constants (B,N,M,D) = (16,1024,4096,256), all fp32.
// Strategy: cross-GEMM on matrix cores via exact 2-term fp16 split
// (e = ae+be, t*2^17 = at+bt), 3 MFMA products ae*at + ae*bt + be*at,
// splits precomputed. Round 23: CONSOLIDATION. score_kernel = r14 champion
// VERBATIM (140us, MfmaUtil 32.6%, VGPR 116, occ 20.2% — best of 22 rounds;
// all structural departures r8-r22 regressed: dbuf/DMA/E-direct/LDS-table
// all lose on the VALU/VGPR/occupancy triangle). New: split+rowsq merged
// into ONE launch (block-range dispatch, block-uniform branch) — saves a
// kernel launch+gap from the ~13us aux overhead.
// Numerics FROZEN (absmax=0 rounds 6-22): identical split values, identical
// per-accumulator MFMA chain order (p1=hi*hi, p2=hi*Tlo, p3=Elo*hi),
// identical epilogue d2 = fl(fl(esq - 2*cross) + tsq), ascending-column
// candidate order, strict '<' + min-index ties, np-pairwise esq/tsq.

typedef _Float16 half8 __attribute__((ext_vector_type(8)));
typedef float f32x4 __attribute__((ext_vector_type(4)));

constexpr int B_ = 16, N_ = 1024, M_ = 4096, D_ = 256;
constexpr int ROWS = B_ * N_;      // 16384 query rows
constexpr int BR = 128;            // rows per block
constexpr int BC = 128;            // cols per col-tile
constexpr int NCT = 4;             // col-tiles per block
constexpr int CS = 8;              // col splits (blockIdx.y)
constexpr int CPB = BC * NCT;      // 512 cols per block
constexpr int KC = 32;             // k per chunk = one 16x16x32 MFMA-K
constexpr int LDH = 32;            // LDS halfs/row: 64B rows
constexpr int NPART = CS * 2;      // 16 partials per row (2 col-half waves)
constexpr float TSCALE = 131072.0f;        // 2^17 (exact)
constexpr float INV2 = 1.52587890625e-05f; // 2^-16: acc*2^-16 == 2*cross, exact

constexpr int SPLIT_BLOCKS = (ROWS + M_) * 32 / 256;  // 2560
constexpr int ROWSQ_BLOCKS = (ROWS + M_) * 16 / 256;  // 1280

// ---------------------------------------------------------------------------
// Kernel A (fused aux): blocks [0, SPLIT_BLOCKS) do the hi/lo fp16 split of
// E and T (T scaled by 2^17, exact); blocks [SPLIT_BLOCKS, +ROWSQ_BLOCKS)
// do the FROZEN numpy-pairwise row sum-of-squares. Both bodies are
// byte-identical to the standalone kernels that passed absmax=0.
// ---------------------------------------------------------------------------
__global__ void aux_kernel(const float* __restrict__ E, const float* __restrict__ T,
                           _Float16* __restrict__ Ehi, _Float16* __restrict__ Elo,
                           _Float16* __restrict__ Thi, _Float16* __restrict__ Tlo,
                           float* __restrict__ esq, float* __restrict__ tsq) {
    if (blockIdx.x < SPLIT_BLOCKS) {
        // ---- split body (FROZEN) ----
        int idx = blockIdx.x * blockDim.x + threadIdx.x;
        int row = idx >> 5;            // 32 threads per 256-elem row
        int c8 = (idx & 31) * 8;
        if (row >= ROWS + M_) return;
        const float* src;
        _Float16 *hi, *lo;
        size_t off;
        float scale;
        if (row < ROWS) {
            off = (size_t)row * D_ + c8;
            src = E + off; hi = Ehi; lo = Elo; scale = 1.0f;
        } else {
            off = (size_t)(row - ROWS) * D_ + c8;
            src = T + off; hi = Thi; lo = Tlo; scale = TSCALE;
        }
        float x[8];
        *reinterpret_cast<float4*>(&x[0]) = *reinterpret_cast<const float4*>(src);
        *reinterpret_cast<float4*>(&x[4]) = *reinterpret_cast<const float4*>(src + 4);
        half8 h, l;
        #pragma unroll
        for (int j = 0; j < 8; j++) {
            float xs = x[j] * scale;               // exact for T (pow2), 1.0 for E
            _Float16 hh = (_Float16)xs;            // RN
            h[j] = hh;
            l[j] = (_Float16)(xs - (float)hh);
        }
        *reinterpret_cast<half8*>(hi + off) = h;
        *reinterpret_cast<half8*>(lo + off) = l;
    } else {
        // ---- rowsq body (FROZEN: numpy pairwise bit-exact for n=256) ----
        int gt = (blockIdx.x - SPLIT_BLOCKS) * blockDim.x + threadIdx.x;
        int row = gt >> 4;
        int l = gt & 15;
        if (row >= ROWS + M_) return;
        const float* src = (row < ROWS) ? (E + (size_t)row * D_)
                                        : (T + (size_t)(row - ROWS) * D_);
        const float* p = src + (l >> 3) * 128 + (l & 7);
        float r = __fmul_rn(p[0], p[0]);
        #pragma unroll
        for (int i = 1; i < 16; i++) {
            float x = p[8 * i];
            r = __fadd_rn(r, __fmul_rn(x, x));
        }
        float u = __fadd_rn(r, __shfl_xor(r, 1, 64));
        float v = __fadd_rn(u, __shfl_xor(u, 2, 64));
        float w = __fadd_rn(v, __shfl_xor(v, 4, 64));
        float s = __fadd_rn(w, __shfl_xor(w, 8, 64));
        if (l == 0) {
            if (row < ROWS) esq[row] = s;
            else            tsq[row - ROWS] = s;
        }
    }
}

// ---------------------------------------------------------------------------
// Kernel 2 (r14 CHAMPION, VERBATIM): MFMA fused GEMM + argmin of
// d2 = fl(fl(esq - 2*cross) + tsq).
// 256 threads = 4 waves (2x2 of 64x64); wave = 4x4 frags of 16x16x32_f16.
// Single-buffered LDS, 2 barriers/chunk, reg staging, 64B LDS rows,
// persistent best/bidx registers.
// ---------------------------------------------------------------------------
__global__ __launch_bounds__(256) void score_kernel(
    const _Float16* __restrict__ Ehi_g, const _Float16* __restrict__ Elo_g,
    const _Float16* __restrict__ Thi_g, const _Float16* __restrict__ Tlo_g,
    const float* __restrict__ esq, const float* __restrict__ tsq,
    float2* __restrict__ part) {
    __shared__ _Float16 Ehi[BR][LDH];
    __shared__ _Float16 Elo[BR][LDH];
    __shared__ _Float16 Thi[BC][LDH];
    __shared__ _Float16 Tlo[BC][LDH];

    const int tid = threadIdx.x;
    const int w  = tid >> 6;       // wave 0..3
    const int l  = tid & 63;
    const int wr = w >> 1;         // row half (0/1)
    const int wc = w & 1;          // col half (0/1)
    const int q  = l >> 4;         // lane quarter
    const int cl = l & 15;         // col-in-frag
    const int row0 = blockIdx.x * BR;
    const int cs = blockIdx.y;
    const int colB = cs * CPB;

    const int srow  = tid >> 1;         // staging row 0..127
    const int skoff = (tid & 1) * 16;   // staging k offset 0/16

    // Per-lane esq values for the 16 (fr,reg) row slots (reused all ct).
    float er[16];
    #pragma unroll
    for (int fr = 0; fr < 4; fr++)
        #pragma unroll
        for (int rg = 0; rg < 4; rg++)
            er[fr * 4 + rg] = esq[row0 + wr * 64 + fr * 16 + q * 4 + rg];

    float best[16];
    int   bidx[16];
    #pragma unroll
    for (int i = 0; i < 16; i++) { best[i] = 3.4e38f; bidx[i] = 0; }

    for (int ct = 0; ct < NCT; ct++) {
        const int col0 = colB + ct * BC;
        f32x4 acc[4][4];
        #pragma unroll
        for (int i = 0; i < 4; i++)
            #pragma unroll
            for (int j = 0; j < 4; j++)
                acc[i][j] = (f32x4){0.f, 0.f, 0.f, 0.f};

        for (int kc = 0; kc < D_; kc += KC) {
            __syncthreads();   // protect LDS from previous chunk's readers
            // --- stage E and T fp16 chunks (pure copies, no conversion) ---
            {
                const size_t eo = (size_t)(row0 + srow) * D_ + kc + skoff;
                half8 eh0 = *reinterpret_cast<const half8*>(Ehi_g + eo);
                half8 eh1 = *reinterpret_cast<const half8*>(Ehi_g + eo + 8);
                half8 el0 = *reinterpret_cast<const half8*>(Elo_g + eo);
                half8 el1 = *reinterpret_cast<const half8*>(Elo_g + eo + 8);
                const size_t to = (size_t)(colB + ct * BC + srow) * D_ + kc + skoff;
                half8 th0 = *reinterpret_cast<const half8*>(Thi_g + to);
                half8 th1 = *reinterpret_cast<const half8*>(Thi_g + to + 8);
                half8 tl0 = *reinterpret_cast<const half8*>(Tlo_g + to);
                half8 tl1 = *reinterpret_cast<const half8*>(Tlo_g + to + 8);
                *reinterpret_cast<half8*>(&Ehi[srow][skoff])     = eh0;
                *reinterpret_cast<half8*>(&Ehi[srow][skoff + 8]) = eh1;
                *reinterpret_cast<half8*>(&Elo[srow][skoff])     = el0;
                *reinterpret_cast<half8*>(&Elo[srow][skoff + 8]) = el1;
                *reinterpret_cast<half8*>(&Thi[srow][skoff])     = th0;
                *reinterpret_cast<half8*>(&Thi[srow][skoff + 8]) = th1;
                *reinterpret_cast<half8*>(&Tlo[srow][skoff])     = tl0;
                *reinterpret_cast<half8*>(&Tlo[srow][skoff + 8]) = tl1;
            }
            __syncthreads();

            // --- frags: cache hi-frags, stream lo-frags through tmp ---
            // (identical MFMA order to rounds 6-22: hi*hi, hi*Tlo, Elo*hi)
            half8 ah[4], bh[4], tmp[4];
            #pragma unroll
            for (int f = 0; f < 4; f++)
                ah[f] = *reinterpret_cast<const half8*>(&Ehi[wr * 64 + f * 16 + cl][q * 8]);
            #pragma unroll
            for (int f = 0; f < 4; f++)
                bh[f] = *reinterpret_cast<const half8*>(&Thi[wc * 64 + f * 16 + cl][q * 8]);
            #pragma unroll
            for (int i = 0; i < 4; i++)
                #pragma unroll
                for (int j = 0; j < 4; j++)
                    acc[i][j] = __builtin_amdgcn_mfma_f32_16x16x32_f16(ah[i], bh[j], acc[i][j], 0, 0, 0);
            #pragma unroll
            for (int f = 0; f < 4; f++)
                tmp[f] = *reinterpret_cast<const half8*>(&Tlo[wc * 64 + f * 16 + cl][q * 8]);
            #pragma unroll
            for (int i = 0; i < 4; i++)
                #pragma unroll
                for (int j = 0; j < 4; j++)
                    acc[i][j] = __builtin_amdgcn_mfma_f32_16x16x32_f16(ah[i], tmp[j], acc[i][j], 0, 0, 0);
            #pragma unroll
            for (int f = 0; f < 4; f++)
                tmp[f] = *reinterpret_cast<const half8*>(&Elo[wr * 64 + f * 16 + cl][q * 8]);
            #pragma unroll
            for (int i = 0; i < 4; i++)
                #pragma unroll
                for (int j = 0; j < 4; j++)
                    acc[i][j] = __builtin_amdgcn_mfma_f32_16x16x32_f16(tmp[i], bh[j], acc[i][j], 0, 0, 0);
        }

        // Epilogue: d2 = fl(fl(er - acc*2^-16) + tc); running argmin.
        // Cols ascend within the thread (fc) and across ct -> strict '<'
        // keeps the smallest index, matching np.argmax first-max.
        #pragma unroll
        for (int fc = 0; fc < 4; fc++) {
            const int col = col0 + wc * 64 + fc * 16 + cl;
            const float tc = tsq[col];
            #pragma unroll
            for (int fr = 0; fr < 4; fr++)
                #pragma unroll
                for (int rg = 0; rg < 4; rg++) {
                    const float c2 = acc[fr][fc][rg] * INV2;  // exact scale
                    const float d1 = __fsub_rn(er[fr * 4 + rg], c2);
                    const float d2 = __fadd_rn(d1, tc);
                    const int s = fr * 4 + rg;
                    if (d2 < best[s]) { best[s] = d2; bidx[s] = col; }
                }
        }
    }

    // Cross-lane reduce within each 16-lane quarter (same rows, diff cols).
    #pragma unroll
    for (int s = 0; s < 16; s++) {
        float v = best[s]; int i = bidx[s];
        #pragma unroll
        for (int off = 1; off < 16; off <<= 1) {
            float ov = __shfl_xor(v, off, 64);
            int   oi = __shfl_xor(i, off, 64);
            if (ov < v || (ov == v && oi < i)) { v = ov; i = oi; }
        }
        if (cl == 0) {
            const int row = row0 + wr * 64 + (s >> 2) * 16 + q * 4 + (s & 3);
            part[(size_t)row * NPART + cs * 2 + wc] = make_float2(v, __int_as_float(i));
        }
    }
}

// ---------------------------------------------------------------------------
// Kernel 3: reduce NPART partials per row (min value, min index on ties),
// gather quant = templat[idx] (bitwise copy), write zidx as float.
// ---------------------------------------------------------------------------
__global__ void gather_kernel(const float* __restrict__ T, const float2* __restrict__ part,
                              float* __restrict__ quant, float* __restrict__ zout) {
    int gt = blockIdx.x * blockDim.x + threadIdx.x;
    int w = gt >> 6, lane = gt & 63;
    if (w >= ROWS) return;
    float2 p = part[(size_t)w * NPART];
    float v = p.x; int idx = __float_as_int(p.y);
    #pragma unroll
    for (int c = 1; c < NPART; c++) {
        float2 q = part[(size_t)w * NPART + c];
        int qi = __float_as_int(q.y);
        if (q.x < v || (q.x == v && qi < idx)) { v = q.x; idx = qi; }
    }
    float4 t = *reinterpret_cast<const float4*>(T + (size_t)idx * D_ + lane * 4);
    *reinterpret_cast<float4*>(quant + (size_t)w * D_ + lane * 4) = t;
    if (lane == 0) zout[w] = (float)idx;
}

// ---------------------------------------------------------------------------
extern "C" void kernel_launch(void* const* d_in, const int* in_sizes, int n_in,
                              void* d_out, int out_size, void* d_ws, size_t ws_size,
                              hipStream_t stream) {
    const float* E = (const float*)d_in[0];   // encode  (B,N,D)
    const float* T = (const float*)d_in[1];   // templat (M,D)
    float* quant = (float*)d_out;                        // (B,N,D) fp32
    float* zout  = quant + (size_t)ROWS * D_;            // (B,N) idx as fp32

    // ws layout: esq[ROWS], tsq[M], part[ROWS*NPART], fp16 Ehi/Elo/Thi/Tlo.
    float* esq   = (float*)d_ws;
    float* tsq   = esq + ROWS;
    float2* part = (float2*)(tsq + M_);
    _Float16* Ehi = (_Float16*)(part + (size_t)ROWS * NPART);
    _Float16* Elo = Ehi + (size_t)ROWS * D_;
    _Float16* Thi = Elo + (size_t)ROWS * D_;
    _Float16* Tlo = Thi + (size_t)M_ * D_;

    hipLaunchKernelGGL(aux_kernel, dim3(SPLIT_BLOCKS + ROWSQ_BLOCKS), dim3(256), 0, stream,
                       E, T, Ehi, Elo, Thi, Tlo, esq, tsq);
    hipLaunchKernelGGL(score_kernel, dim3(ROWS / BR, CS), dim3(256), 0, stream,
                       Ehi, Elo, Thi, Tlo, esq, tsq, part);
    hipLaunchKernelGGL(gather_kernel, dim3(ROWS * 64 / 256), dim3(256), 0, stream, T, part, quant, zout);
}